// Round 1
// baseline (45.355 us; speedup 1.0000x reference)
//
#include <hip/hip_runtime.h>
#include <cstdint>

namespace {

constexpr int NB = 320;   // batch
constexpr int ND = 128;   // feature dim
constexpr int NC = 80;    // label dim
constexpr int NANCH = 30;

// ---- workspace layout (byte offsets) ----
constexpr size_t OFF_FD   = 0;          // float[320*320] = 409600 B
constexpr size_t OFF_PACK = 409600;     // u64 [320*2]    = 5120 B
constexpr size_t OFF_NS   = 414720;     // float[320]
constexpr size_t OFF_NT   = 416000;     // float[320]
constexpr size_t OFF_CNT  = 417280;     // float[320]  (label row popcount)
constexpr size_t OFF_DIV  = 418560;     // float[320]
constexpr size_t OFF_FLAG = 419840;     // int[320]
constexpr size_t OFF_ASUM = 421120;     // double[320] (8-aligned)
constexpr size_t OFF_ACNT = 423680;     // int[320]
// total ~425 KB

__device__ __forceinline__ float waveReduceSumF(float v) {
    for (int off = 32; off > 0; off >>= 1) v += __shfl_down(v, off);
    return v;
}

// K1: source/target row norms, packed label bitmasks, label popcounts.
__global__ __launch_bounds__(64) void k_prep(const int* __restrict__ label,
                                             const float* __restrict__ src,
                                             const float* __restrict__ tgt,
                                             float* __restrict__ ns,
                                             float* __restrict__ nt,
                                             float* __restrict__ cntf,
                                             unsigned long long* __restrict__ packed) {
    const int i = blockIdx.x;
    const int lane = threadIdx.x;

    float s0 = src[i * ND + lane];
    float s1 = src[i * ND + lane + 64];
    float v = waveReduceSumF(s0 * s0 + s1 * s1);
    if (lane == 0) ns[i] = sqrtf(v);

    float t0 = tgt[i * ND + lane];
    float t1 = tgt[i * ND + lane + 64];
    float w = waveReduceSumF(t0 * t0 + t1 * t1);
    if (lane == 0) nt[i] = sqrtf(w);

    int l0 = label[i * NC + lane];                         // lanes 0..63 -> c 0..63
    int l1 = (lane < NC - 64) ? label[i * NC + 64 + lane] : 0; // lanes 0..15 -> c 64..79
    unsigned long long b0 = __ballot(l0 != 0);
    unsigned long long b1 = __ballot(l1 != 0);
    if (lane == 0) {
        packed[2 * i]     = b0;
        packed[2 * i + 1] = b1;
        cntf[i] = (float)(__popcll(b0) + __popcll(b1));
    }
}

// K2: fd[a,:] = clip(1 - cos_sim, 0) and diversity[a] = mean(fd[a,:]).
__global__ __launch_bounds__(256) void k_fd(const float* __restrict__ src,
                                            const float* __restrict__ tgt,
                                            const float* __restrict__ ns,
                                            const float* __restrict__ nt,
                                            float* __restrict__ fd,
                                            float* __restrict__ divr) {
    const int a = blockIdx.x;
    const int tid = threadIdx.x;
    __shared__ float sa[ND];
    __shared__ float red[256];
    if (tid < ND) sa[tid] = src[a * ND + tid];
    __syncthreads();

    const float nsa = ns[a];
    float acc = 0.f;
    for (int j = tid; j < NB; j += 256) {
        const float4* tp = reinterpret_cast<const float4*>(tgt + j * ND);
        float dot = 0.f;
#pragma unroll
        for (int d4 = 0; d4 < ND / 4; ++d4) {
            float4 t = tp[d4];
            dot += sa[4 * d4 + 0] * t.x + sa[4 * d4 + 1] * t.y +
                   sa[4 * d4 + 2] * t.z + sa[4 * d4 + 3] * t.w;
        }
        float sim = dot / fmaxf(nsa * nt[j], 1e-8f);
        float f = fmaxf(1.0f - sim, 0.0f);
        fd[a * NB + j] = f;
        acc += f;
    }
    red[tid] = acc;
    __syncthreads();
    for (int s = 128; s > 0; s >>= 1) {
        if (tid < s) red[tid] += red[tid + s];
        __syncthreads();
    }
    if (tid == 0) divr[a] = red[0] / (float)NB;
}

// K3: top-30 diversity selection (ties -> lowest index, matching lax.top_k).
__global__ __launch_bounds__(64) void k_anchor(const float* __restrict__ divr,
                                               int* __restrict__ flags) {
    __shared__ float dv[NB];
    __shared__ int fl[NB];
    const int lane = threadIdx.x;
#pragma unroll
    for (int t = 0; t < 5; ++t) {
        dv[lane + 64 * t] = divr[lane + 64 * t];
        fl[lane + 64 * t] = 0;
    }
    __syncthreads();
    for (int r = 0; r < NANCH; ++r) {
        float bv = -1e30f;
        int bi = NB;
#pragma unroll
        for (int t = 0; t < 5; ++t) {
            int idx = lane + 64 * t;
            float v = dv[idx];
            if (v > bv) { bv = v; bi = idx; }   // ascending idx scan keeps lowest idx on tie
        }
        for (int off = 32; off > 0; off >>= 1) {
            float ov = __shfl_xor(bv, off);
            int oi = __shfl_xor(bi, off);
            if (ov > bv || (ov == bv && oi < bi)) { bv = ov; bi = oi; }
        }
        if (lane == 0) { dv[bi] = -1e30f; fl[bi] = 1; }
        __syncthreads();
    }
#pragma unroll
    for (int t = 0; t < 5; ++t) flags[lane + 64 * t] = fl[lane + 64 * t];
}

// K4: per-anchor triplet sum. pos/neg disjoint (gamma<beta) => p!=n automatic.
__global__ __launch_bounds__(256) void k_triplet(const int* __restrict__ flags,
                                                 const unsigned long long* __restrict__ packed,
                                                 const float* __restrict__ cntf,
                                                 const float* __restrict__ fd,
                                                 double* __restrict__ asum,
                                                 int* __restrict__ acnt) {
    const int a = blockIdx.x;
    const int tid = threadIdx.x;
    if (!flags[a]) {
        if (tid == 0) { asum[a] = 0.0; acnt[a] = 0; }
        return;
    }
    __shared__ float fdrow[NB];
    __shared__ unsigned short pl[NB], nl[NB];
    __shared__ int pc, nc;
    __shared__ double dred[4];
    if (tid == 0) { pc = 0; nc = 0; }
    for (int j = tid; j < NB; j += 256) fdrow[j] = fd[a * NB + j];
    const unsigned long long a0 = packed[2 * a], a1 = packed[2 * a + 1];
    const float sna = sqrtf(cntf[a]);
    __syncthreads();

    for (int j = tid; j < NB; j += 256) {
        if (j == a) continue;
        unsigned long long c0 = packed[2 * j], c1 = packed[2 * j + 1];
        float dotf = (float)(__popcll(a0 & c0) + __popcll(a1 & c1));
        float ld = 1.0f - fminf(1.0f, dotf / (sna * sqrtf(cntf[j])));
        if (ld <= 0.2f)      pl[atomicAdd(&pc, 1)] = (unsigned short)j;
        else if (ld >= 0.5f) nl[atomicAdd(&nc, 1)] = (unsigned short)j;
    }
    __syncthreads();

    const int P = pc, N = nc;
    const int total = P * N;
    double s = 0.0;
    for (int idx = tid; idx < total; idx += 256) {
        float fp = fdrow[pl[idx / N]];
        float fn = fdrow[nl[idx % N]];
        float v = fp - fn + 0.5f;
        if (v > 0.f) s += (double)v;
    }
    for (int off = 32; off > 0; off >>= 1) s += __shfl_down(s, off);
    if ((tid & 63) == 0) dred[tid >> 6] = s;
    __syncthreads();
    if (tid == 0) {
        asum[a] = dred[0] + dred[1] + dred[2] + dred[3];
        acnt[a] = total;
    }
}

// K5: deterministic final reduction -> scalar.
__global__ __launch_bounds__(64) void k_final(const double* __restrict__ asum,
                                              const int* __restrict__ acnt,
                                              float* __restrict__ out) {
    const int lane = threadIdx.x;
    double s = 0.0, c = 0.0;
#pragma unroll
    for (int t = 0; t < 5; ++t) {
        s += asum[lane + 64 * t];
        c += (double)acnt[lane + 64 * t];
    }
    for (int off = 32; off > 0; off >>= 1) {
        s += __shfl_down(s, off);
        c += __shfl_down(c, off);
    }
    if (lane == 0) out[0] = (float)(s / (c + 1e-4));
}

} // namespace

extern "C" void kernel_launch(void* const* d_in, const int* in_sizes, int n_in,
                              void* d_out, int out_size, void* d_ws, size_t ws_size,
                              hipStream_t stream) {
    const int* label   = (const int*)d_in[0];
    const float* src   = (const float*)d_in[1];
    const float* tgt   = (const float*)d_in[2];

    char* ws = (char*)d_ws;
    float* fd    = (float*)(ws + OFF_FD);
    unsigned long long* packed = (unsigned long long*)(ws + OFF_PACK);
    float* ns    = (float*)(ws + OFF_NS);
    float* nt    = (float*)(ws + OFF_NT);
    float* cntf  = (float*)(ws + OFF_CNT);
    float* divr  = (float*)(ws + OFF_DIV);
    int*   flags = (int*)(ws + OFF_FLAG);
    double* asum = (double*)(ws + OFF_ASUM);
    int*   acnt  = (int*)(ws + OFF_ACNT);

    k_prep   <<<NB, 64, 0, stream>>>(label, src, tgt, ns, nt, cntf, packed);
    k_fd     <<<NB, 256, 0, stream>>>(src, tgt, ns, nt, fd, divr);
    k_anchor <<<1, 64, 0, stream>>>(divr, flags);
    k_triplet<<<NB, 256, 0, stream>>>(flags, packed, cntf, fd, asum, acnt);
    k_final  <<<1, 64, 0, stream>>>(asum, acnt, (float*)d_out);
}